// Round 8
// baseline (96.146 us; speedup 1.0000x reference)
//
#include <hip/hip_runtime.h>
#include <math.h>

#define NS   8      // samples
#define CC   256    // input channels
#define PP   961    // H*W
#define MM   7688   // NS*PP nodes
#define MP   7744   // MM padded to 64
#define HID  512
#define OUTC 256

typedef _Float16 h16;
using half8   = __attribute__((ext_vector_type(8))) _Float16;
using floatx4 = __attribute__((ext_vector_type(4))) float;

#define AS1 __attribute__((address_space(1)))
#define AS3 __attribute__((address_space(3)))

// deg = 963 for b in {0,7}, 964 otherwise; dinv = deg^-0.5
__device__ __forceinline__ float dinv_of(int b) {
    return (b == 0 || b == NS - 1) ? 0.0322245515f : 0.0322078318f;
}

// K0 prep: [0,256): convert W1/W2 -> fp16; [256,2304): colsum_x -> S1; [2304,2312): zero SY
// (tree colsum, 2048 blocks = 32 waves/CU: the latency-bound colsum needs block-level TLP;
//  wave-per-row variant measured +3-4us worse in R1/R4)
__global__ void prep(const float* __restrict__ W1, const float* __restrict__ W2,
                     h16* __restrict__ w1h, h16* __restrict__ w2h,
                     const float* __restrict__ x, float* __restrict__ S1,
                     float* __restrict__ SY) {
    int blk = blockIdx.x, tid = threadIdx.x;
    if (blk < 256) {
        bool second = blk >= 128;
        const float* src = second ? W2 : W1;
        h16* dst = second ? w2h : w1h;
        int i = ((blk & 127) * 256 + tid) * 4;
        float4 v = *(const float4*)(src + i);
        dst[i + 0] = (h16)v.x; dst[i + 1] = (h16)v.y;
        dst[i + 2] = (h16)v.z; dst[i + 3] = (h16)v.w;
    } else if (blk < 2304) {
        int bc = blk - 256;                       // b*CC + c
        const float* src = x + (size_t)bc * PP;
        float s = 0.f;
        for (int i = tid; i < PP; i += 256) s += src[i];
        __shared__ float red[256];
        red[tid] = s;
        __syncthreads();
        for (int off = 128; off > 0; off >>= 1) {
            if (tid < off) red[tid] += red[tid + off];
            __syncthreads();
        }
        if (tid == 0) S1[bc] = red[0];
    } else {
        int i = (blk - 2304) * 256 + tid;         // < 2048
        SY[i] = 0.f;
    }
}

// K1: G1[(b*PP+p)*CC + c] = db^2*(S1[b,c] + x[b,c,p]) + db*(d(b-1)*x[b-1,c,p] + d(b+1)*x[b+1,c,p])
__global__ void build_g1(const float* __restrict__ x, const float* __restrict__ S1,
                         h16* __restrict__ G1) {
    int pt = blockIdx.x, ct = blockIdx.y, b = blockIdx.z;
    int p0 = pt * 32, c0 = ct * 32;
    float db  = dinv_of(b);
    float wm  = (b > 0)      ? db * dinv_of(b - 1) : 0.f;
    float wp  = (b < NS - 1) ? db * dinv_of(b + 1) : 0.f;
    float db2 = db * db;
    __shared__ float t[32][33];
    int j = threadIdx.x & 31, i0 = threadIdx.x >> 5;
    int p = p0 + j;
    bool pv = (p < PP);
    #pragma unroll
    for (int r = 0; r < 4; ++r) {
        int i = i0 + r * 8;
        int c = c0 + i;
        float v = 0.f;
        if (pv) {
            size_t base = ((size_t)b * CC + c) * PP + p;
            float xb = x[base];
            float xm = (b > 0)      ? x[base - (size_t)CC * PP] : 0.f;
            float xp = (b < NS - 1) ? x[base + (size_t)CC * PP] : 0.f;
            v = db2 * (S1[b * CC + c] + xb) + wm * xm + wp * xp;
        }
        t[i][j] = v;
    }
    __syncthreads();
    int ii = threadIdx.x & 31, jj0 = threadIdx.x >> 5;
    #pragma unroll
    for (int r = 0; r < 4; ++r) {
        int jj = jj0 + r * 8;
        int pw = p0 + jj;
        if (pw < PP)
            G1[((size_t)b * PP + pw) * CC + c0 + ii] = (h16)t[ii][jj];
    }
}

// K2/K3: MFMA GEMM, 64x64 tile, BK=128 (halves barrier-drain rounds vs BK=64),
// XOR-swizzled LDS chunks, fp16 in / fp32 acc.
// Staging: per instr, 4 rows x 16 chunks(16B); lane l -> row +(l>>4), slot l&15,
// fetches global chunk (l&15)^(row&15) so LDS slot s of row r holds chunk s^(r&15).
// Read: slot = (ks*4+fq)^fr recovers k-chunk ks*4+fq for row fr (all tile rows
// have row&15==fr). Bank aliasing 2-way (free). Same k accumulation order as BK=64.
// ACT: v = lrelu(acc + bias). DO_SUM: per-sample column sums of raw v -> atomicAdd SY.
template<int KD, bool ACT, bool DO_SUM, typename OutT>
__global__ __launch_bounds__(256) void mfma_gemm(
    const h16* __restrict__ A,    // [MP][KD]
    const h16* __restrict__ B,    // [Nc][KD]  (torch Linear layout)
    const float* __restrict__ bias,
    OutT* __restrict__ C,         // [M][Nc]
    float* __restrict__ SY,       // [NS][Nc] (used when DO_SUM)
    int M, int Nc)
{
    __shared__ __align__(16) h16 As[64 * 128];
    __shared__ __align__(16) h16 Bs[64 * 128];
    int tid = threadIdx.x, wave = tid >> 6, lane = tid & 63;
    int m0 = blockIdx.x * 64, n0 = blockIdx.y * 64;
    int sro = lane >> 4;          // row within 4-row instr group
    int sc  = lane & 15;          // lds slot
    int fr = lane & 15, fq = lane >> 4;
    floatx4 acc[4] = {{0.f,0.f,0.f,0.f},{0.f,0.f,0.f,0.f},{0.f,0.f,0.f,0.f},{0.f,0.f,0.f,0.f}};
    for (int kk = 0; kk < KD; kk += 128) {
        #pragma unroll
        for (int i = 0; i < 4; ++i) {
            int r16 = i * 4 + sro;                          // row & 15
            int gch = (sc ^ r16) * 8;                       // fetched k-chunk offset (h16)
            const h16* ga = A + (size_t)(m0 + wave * 16 + r16) * KD + kk + gch;
            const h16* gb = B + (size_t)(n0 + wave * 16 + r16) * KD + kk + gch;
            __builtin_amdgcn_global_load_lds((const AS1 void*)(const void*)ga,
                                             (AS3 void*)(void*)&As[(wave * 16 + i * 4) * 128], 16, 0, 0);
            __builtin_amdgcn_global_load_lds((const AS1 void*)(const void*)gb,
                                             (AS3 void*)(void*)&Bs[(wave * 16 + i * 4) * 128], 16, 0, 0);
        }
        __syncthreads();
        #pragma unroll
        for (int ks = 0; ks < 4; ++ks) {
            int slot = (ks * 4 + fq) ^ fr;
            half8 bf = *(const half8*)&Bs[(wave * 16 + fr) * 128 + slot * 8];
            #pragma unroll
            for (int mb = 0; mb < 4; ++mb) {
                half8 af = *(const half8*)&As[(mb * 16 + fr) * 128 + slot * 8];
                acc[mb] = __builtin_amdgcn_mfma_f32_16x16x32_f16(af, bf, acc[mb], 0, 0, 0);
            }
        }
        __syncthreads();
    }
    int col = n0 + wave * 16 + fr;
    float bv = ACT ? bias[col] : 0.f;
    float s_lo = 0.f, s_hi = 0.f;
    int blo = m0 / 961;
    int mcut = (blo + 1) * 961;
    #pragma unroll
    for (int mb = 0; mb < 4; ++mb) {
        #pragma unroll
        for (int r = 0; r < 4; ++r) {
            int m = m0 + mb * 16 + fq * 4 + r;
            if (m < M) {
                float v = acc[mb][r] + bv;
                if (ACT) v = (v >= 0.f) ? v : 0.01f * v;
                C[(size_t)m * Nc + col] = (OutT)v;
                if (DO_SUM) { if (m < mcut) s_lo += v; else s_hi += v; }
            }
        }
    }
    if (DO_SUM) {
        s_lo += __shfl_xor(s_lo, 16);
        s_lo += __shfl_xor(s_lo, 32);
        s_hi += __shfl_xor(s_hi, 16);
        s_hi += __shfl_xor(s_hi, 32);
        if (fq == 0) {
            atomicAdd(&SY[blo * Nc + col], s_lo);
            int bhi = (m0 + 63) / 961;
            if (bhi != blo && bhi < NS) atomicAdd(&SY[bhi * Nc + col], s_hi);
        }
    }
}

// K4: out[o*PP+p] = max_b lrelu( b2[o] + db*( db*(SY[b,o]+Y[b,p,o]) + dm*Y[b-1,p,o] + dp*Y[b+1,p,o] ) )
__global__ void final_max(const float* __restrict__ Y, const float* __restrict__ SY,
                          const float* __restrict__ b2, float* __restrict__ out) {
    int pt = blockIdx.x, ot = blockIdx.y;
    int p0 = pt * 32, o0 = ot * 32;
    __shared__ float t[32][33];
    int i = threadIdx.x & 31, j0 = threadIdx.x >> 5;
    int o = o0 + i;
    float bias = b2[o];
    #pragma unroll
    for (int r = 0; r < 4; ++r) {
        int j = j0 + r * 8;
        int p = p0 + j;
        float vmax = -INFINITY;
        if (p < PP) {
            float y[NS];
            #pragma unroll
            for (int b = 0; b < NS; ++b)
                y[b] = Y[((size_t)b * PP + p) * OUTC + o];
            #pragma unroll
            for (int b = 0; b < NS; ++b) {
                float db = dinv_of(b);
                float a = db * (SY[b * OUTC + o] + y[b]);
                if (b > 0)      a += dinv_of(b - 1) * y[b - 1];
                if (b < NS - 1) a += dinv_of(b + 1) * y[b + 1];
                float z = db * a + bias;
                z = (z >= 0.f) ? z : 0.01f * z;
                vmax = fmaxf(vmax, z);
            }
        }
        t[j][i] = vmax;
    }
    __syncthreads();
    int jj = threadIdx.x & 31, ii0 = threadIdx.x >> 5;
    #pragma unroll
    for (int r = 0; r < 4; ++r) {
        int ii = ii0 + r * 8;
        int pw = p0 + jj;
        if (pw < PP)
            out[(size_t)(o0 + ii) * PP + pw] = t[jj][ii];
    }
}

extern "C" void kernel_launch(void* const* d_in, const int* in_sizes, int n_in,
                              void* d_out, int out_size, void* d_ws, size_t ws_size,
                              hipStream_t stream) {
    const float* x  = (const float*)d_in[0];
    const float* W1 = (const float*)d_in[1];
    const float* b1 = (const float*)d_in[2];
    const float* W2 = (const float*)d_in[3];
    const float* b2 = (const float*)d_in[4];
    float* out = (float*)d_out;
    float* ws  = (float*)d_ws;

    // workspace layout (float offsets, all 16B-aligned)
    float* S1  = ws;                        //      2,048 f
    float* SY  = ws + 2048;                 //      2,048 f (NS*OUTC)
    h16*  w1h  = (h16*)(ws + 4096);         //  131,072 h =  65,536 f
    h16*  w2h  = (h16*)(ws + 69632);        //  131,072 h
    h16*  G1   = (h16*)(ws + 135168);       //  MP*CC  h =  991,232 f
    h16*  H1   = (h16*)(ws + 1126400);      //  MP*HID h = 1,982,464 f (pad rows stay poison: finite)
    float* Y   = ws + 3108864;              //  MM*OUTC f = 1,968,128 f -> end 5,076,992 f (20.3 MB)

    prep<<<2312, 256, 0, stream>>>(W1, W2, w1h, w2h, x, S1, SY);
    build_g1<<<dim3(31, 8, NS), 256, 0, stream>>>(x, S1, G1);
    mfma_gemm<CC, true, false, h16><<<dim3(MP / 64, HID / 64), 256, 0, stream>>>(
        G1, w1h, b1, H1, nullptr, MM, HID);
    mfma_gemm<HID, false, true, float><<<dim3(MP / 64, OUTC / 64), 256, 0, stream>>>(
        H1, w2h, nullptr, Y, SY, MM, OUTC);
    final_max<<<dim3(31, 8), 256, 0, stream>>>(Y, SY, b2, out);
}